// Round 2
// baseline (1099.485 us; speedup 1.0000x reference)
//
#include <hip/hip_runtime.h>
#include <hip/hip_bf16.h>

typedef __bf16 v8bf __attribute__((ext_vector_type(8)));
typedef float  v4f  __attribute__((ext_vector_type(4)));

#define MFMA(a,b,c) __builtin_amdgcn_mfma_f32_16x16x32_bf16((a),(b),(c),0,0,0)

__device__ __forceinline__ float loadf(const void* p, int i, int isb) {
  return isb ? (float)(((const __bf16*)p)[i]) : ((const float*)p)[i];
}

// ---- K1: dtype detector (bf16 vs fp32 storage of float arrays) ----------
__global__ void detect_kernel(const void* __restrict__ x, int* __restrict__ flag) {
  __shared__ int cnt;
  if (threadIdx.x == 0) cnt = 0;
  __syncthreads();
  unsigned char b = ((const unsigned char*)x)[1 + 4 * (int)threadIdx.x];
  int e = b & 0x7f;
  if (e >= 0x3B && e <= 0x41) atomicAdd(&cnt, 1);
  __syncthreads();
  if (threadIdx.x == 0) *flag = (cnt >= 64) ? 1 : 0;
}

// ---- K2: weight repack (B-fragment order, bf16) + cmb = rpb + mask ------
// cmb layout: within each 64-col row, value for col j=jj*16+c16 stored at
// position c16*4+jj  -> wattn reads one float4 per (row, lane c16).
__global__ void prep_kernel(const void* __restrict__ qkv_w, const void* __restrict__ proj_w,
                            const void* __restrict__ bias_table, const int* __restrict__ rel_idx,
                            const void* __restrict__ mask, const int* __restrict__ flag,
                            __bf16* __restrict__ qkv_wf, __bf16* __restrict__ projf,
                            float* __restrict__ cmb) {
  const int isb = *flag;
  int e = blockIdx.x * 256 + threadIdx.x;
  if (e < 110592) {
    int j = e & 7, lx = (e >> 3) & 63, ks = (e >> 9) % 6, nt = e / 3072;
    int n = nt * 16 + (lx & 15), k = ks * 32 + (lx >> 4) * 8 + j;
    qkv_wf[e] = (__bf16)loadf(qkv_w, n * 192 + k, isb);
  } else if (e < 147456) {
    int e2 = e - 110592;
    int j = e2 & 7, lx = (e2 >> 3) & 63, ks = (e2 >> 9) % 6, nt = e2 / 3072;
    int n = nt * 16 + (lx & 15), k = ks * 32 + (lx >> 4) * 8 + j;
    projf[e2] = (__bf16)loadf(proj_w, n * 192 + k, isb);
  } else if (e < 147456 + 1572864) {
    int e2 = e - 147456;
    int j = e2 & 63, i = (e2 >> 6) & 63, hh = (e2 >> 12) % 6, w = e2 / 24576;
    float v = loadf(bias_table, rel_idx[i * 64 + j] * 6 + hh, isb)
            + loadf(mask, (w * 64 + i) * 64 + j, isb);
    cmb[(e2 & ~63) | (((j & 15) << 2) | (j >> 4))] = v;
  }
}

// ---- K3: fused window attention. 1 block = 1 window, 6 waves = 6 heads --
// LDS cut 72KB -> 48KB so 2 blocks/CU co-reside under any plausible LDS cap:
//  [0,24K):  x A-frags (phase1), then vf (per-head 4KB slot)
//  [24K,48K): per-head 4KB scratch (q bounce -> k bounce -> P bounce 2KB),
//             then Of (24KB) for the proj phase.
// q/k/P never coexist in LDS: each is written and immediately re-read into
// registers by the SAME wave (in-order DS pipeline makes this safe).
__global__ __launch_bounds__(384, 3)
void wattn_kernel(const void* __restrict__ x, const int* __restrict__ flag,
                  const __bf16* __restrict__ qkv_wf, const __bf16* __restrict__ projf,
                  const float* __restrict__ cmb,
                  const void* __restrict__ qkv_b, const void* __restrict__ proj_b,
                  void* __restrict__ out) {
  __shared__ char smem[49152];
  __bf16* xf = (__bf16*)smem;             // 24KB
  __bf16* Qs = (__bf16*)(smem + 24576);   // 24KB

  const int isb = *flag;
  const int win = blockIdx.x;
  const int t = threadIdx.x;
  const int l = t & 63;
  const int h = t >> 6;
  const int quad = l >> 4;
  const int c16 = l & 15;
  const float SCALE = 0.17677669529663687f;   // 32^-0.5

  // ---- stage x (64x192) into A-fragment order, bf16 ----
  #pragma unroll
  for (int i = 0; i < 4; ++i) {
    int c = t + i * 384;                      // c in [0,1536): 8 consecutive k's
    int tok = c / 24, kb8 = c % 24;
    v8bf v;
    if (isb) {
      v = *(const v8bf*)((const __bf16*)x + (size_t)win * 12288 + (size_t)c * 8);
    } else {
      const float* xp = (const float*)x + (size_t)win * 12288 + (size_t)c * 8;
      float4 f0 = ((const float4*)xp)[0];
      float4 f1 = ((const float4*)xp)[1];
      v8bf tv;
      tv[0]=(__bf16)f0.x; tv[1]=(__bf16)f0.y; tv[2]=(__bf16)f0.z; tv[3]=(__bf16)f0.w;
      tv[4]=(__bf16)f1.x; tv[5]=(__bf16)f1.y; tv[6]=(__bf16)f1.z; tv[7]=(__bf16)f1.w;
      v = tv;
    }
    int mt = tok >> 4, r = tok & 15, ks = kb8 >> 2, kb = kb8 & 3;
    *(v8bf*)(xf + ((mt * 6 + ks) * 64 + kb * 16 + r) * 8) = v;
  }
  __syncthreads();

  const v4f vzero = {0.f, 0.f, 0.f, 0.f};
  __bf16* sq = Qs + h * 2048;      // per-head 4KB scratch

  v8bf aq[4], bk[4];

  // ---- phase 1-qk: q then k projection, bounced through sq into regs ----
  #pragma unroll
  for (int pass = 0; pass < 2; ++pass) {
    v4f acc[2][4];
    #pragma unroll
    for (int n = 0; n < 2; ++n)
      #pragma unroll
      for (int m = 0; m < 4; ++m) acc[n][m] = vzero;

    #pragma unroll
    for (int ks = 0; ks < 6; ++ks) {
      v8bf a[4];
      #pragma unroll
      for (int mt = 0; mt < 4; ++mt) a[mt] = *(const v8bf*)(xf + ((mt * 6 + ks) * 64 + l) * 8);
      #pragma unroll
      for (int nl = 0; nl < 2; ++nl) {
        int nt = pass * 12 + 2 * h + nl;
        v8bf b = *(const v8bf*)(qkv_wf + ((nt * 6 + ks) * 64 + l) * 8);
        #pragma unroll
        for (int mt = 0; mt < 4; ++mt) acc[nl][mt] = MFMA(a[mt], b, acc[nl][mt]);
      }
    }
    float mul = pass ? 1.0f : SCALE;
    #pragma unroll
    for (int nl = 0; nl < 2; ++nl) {
      int hd = nl * 16 + c16;
      float bias = loadf(qkv_b, pass * 192 + h * 32 + hd, isb);
      #pragma unroll
      for (int mt = 0; mt < 4; ++mt)
        #pragma unroll
        for (int reg = 0; reg < 4; ++reg) {
          float vv = (acc[nl][mt][reg] + bias) * mul;
          int u = mt * 64 + (hd >> 3) * 16 + quad * 4 + reg;
          sq[u * 8 + (hd & 7)] = (__bf16)vv;
        }
    }
    if (pass == 0) {
      #pragma unroll
      for (int mt = 0; mt < 4; ++mt) aq[mt] = *(const v8bf*)(sq + (mt * 64 + l) * 8);
    } else {
      #pragma unroll
      for (int j = 0; j < 4; ++j) bk[j] = *(const v8bf*)(sq + (j * 64 + l) * 8);
    }
  }

  // ---- phase 1-v: v projection (M=64,N=32,K=192), still reads xf ----
  v4f vac[2][4];
  #pragma unroll
  for (int n = 0; n < 2; ++n)
    #pragma unroll
    for (int m = 0; m < 4; ++m) vac[n][m] = vzero;
  #pragma unroll
  for (int ks = 0; ks < 6; ++ks) {
    v8bf a[4];
    #pragma unroll
    for (int mt = 0; mt < 4; ++mt) a[mt] = *(const v8bf*)(xf + ((mt * 6 + ks) * 64 + l) * 8);
    #pragma unroll
    for (int ntl = 0; ntl < 2; ++ntl) {
      int nt = 24 + 2 * h + ntl;
      v8bf b = *(const v8bf*)(qkv_wf + ((nt * 6 + ks) * 64 + l) * 8);
      #pragma unroll
      for (int mt = 0; mt < 4; ++mt) vac[ntl][mt] = MFMA(a[mt], b, vac[ntl][mt]);
    }
  }
  __syncthreads();   // all waves done reading xf -> x region reusable

  __bf16* vf = xf + h * 2048;      // V in B-frag order (K=token', N=hd)
  #pragma unroll
  for (int ntl = 0; ntl < 2; ++ntl) {
    float bias = loadf(qkv_b, 384 + h * 32 + ntl * 16 + c16, isb);
    #pragma unroll
    for (int mt = 0; mt < 4; ++mt)
      #pragma unroll
      for (int reg = 0; reg < 4; ++reg) {
        int mrow = quad * 4 + reg;
        int u = (ntl * 2 + (mt >> 1)) * 64 + ((mt & 1) * 2 + (mrow >> 3)) * 16 + c16;
        vf[u * 8 + (mrow & 7)] = (__bf16)(vac[ntl][mt][reg] + bias);
      }
  }

  // ---- phase 2 (fused): scores + bias/mask + softmax + PV, per 16-row mt --
  v8bf bv[2][2];
  #pragma unroll
  for (int ksb = 0; ksb < 2; ++ksb)
    #pragma unroll
    for (int ntb = 0; ntb < 2; ++ntb)
      bv[ksb][ntb] = *(const v8bf*)(vf + ((ntb * 2 + ksb) * 64 + l) * 8);

  v4f o[4][2];
  #pragma unroll
  for (int m = 0; m < 4; ++m) { o[m][0] = vzero; o[m][1] = vzero; }

  {
    const float* cb = cmb + (size_t)((win & 63) * 6 + h) * 4096;
    #pragma unroll
    for (int mt = 0; mt < 4; ++mt) {
      v4f sc[4];
      #pragma unroll
      for (int j = 0; j < 4; ++j) sc[j] = MFMA(aq[mt], bk[j], vzero);
      #pragma unroll
      for (int reg = 0; reg < 4; ++reg) {
        int mrow = quad * 4 + reg;
        int row = mt * 16 + mrow;
        float4 cv = *(const float4*)(cb + row * 64 + c16 * 4);
        float v0 = sc[0][reg] + cv.x;
        float v1 = sc[1][reg] + cv.y;
        float v2 = sc[2][reg] + cv.z;
        float v3 = sc[3][reg] + cv.w;
        float mx = fmaxf(fmaxf(v0, v1), fmaxf(v2, v3));
        mx = fmaxf(mx, __shfl_xor(mx, 1));
        mx = fmaxf(mx, __shfl_xor(mx, 2));
        mx = fmaxf(mx, __shfl_xor(mx, 4));
        mx = fmaxf(mx, __shfl_xor(mx, 8));
        float p0 = __expf(v0 - mx), p1 = __expf(v1 - mx);
        float p2 = __expf(v2 - mx), p3 = __expf(v3 - mx);
        float sm = p0 + p1 + p2 + p3;
        sm += __shfl_xor(sm, 1);
        sm += __shfl_xor(sm, 2);
        sm += __shfl_xor(sm, 4);
        sm += __shfl_xor(sm, 8);
        float inv = 1.0f / sm;
        float pn[4] = {p0 * inv, p1 * inv, p2 * inv, p3 * inv};
        #pragma unroll
        for (int j = 0; j < 4; ++j) {
          int u = (j >> 1) * 64 + ((j & 1) * 2 + (c16 >> 3)) * 16 + mrow;
          sq[u * 8 + (c16 & 7)] = (__bf16)pn[j];   // P bounce (2KB, reused per mt)
        }
      }
      v8bf ap0 = *(const v8bf*)(sq + l * 8);
      v8bf ap1 = *(const v8bf*)(sq + (64 + l) * 8);
      o[mt][0] = MFMA(ap0, bv[0][0], o[mt][0]);
      o[mt][1] = MFMA(ap0, bv[0][1], o[mt][1]);
      o[mt][0] = MFMA(ap1, bv[1][0], o[mt][0]);
      o[mt][1] = MFMA(ap1, bv[1][1], o[mt][1]);
    }
  }
  __syncthreads();   // all P-bounce/vf reads done before Of overwrites scratch

  __bf16* Of = Qs;   // O (64x192) in A-frag order; wave h supplies k-step ks=h
  #pragma unroll
  for (int mt = 0; mt < 4; ++mt)
    #pragma unroll
    for (int ntb = 0; ntb < 2; ++ntb)
      #pragma unroll
      for (int reg = 0; reg < 4; ++reg) {
        int u = (mt * 6 + h) * 64 + (ntb * 2 + (c16 >> 3)) * 16 + quad * 4 + reg;
        Of[u * 8 + (c16 & 7)] = (__bf16)o[mt][ntb][reg];
      }
  __syncthreads();

  // ---- phase 3: out = O @ proj_w^T + proj_b (M=64,N=192,K=192) ----
  v4f pa[2][4];
  #pragma unroll
  for (int n = 0; n < 2; ++n)
    #pragma unroll
    for (int m = 0; m < 4; ++m) pa[n][m] = vzero;
  #pragma unroll
  for (int ks = 0; ks < 6; ++ks) {
    v8bf a[4];
    #pragma unroll
    for (int mt = 0; mt < 4; ++mt) a[mt] = *(const v8bf*)(Of + ((mt * 6 + ks) * 64 + l) * 8);
    #pragma unroll
    for (int ntl = 0; ntl < 2; ++ntl) {
      int nt = 2 * h + ntl;
      v8bf b = *(const v8bf*)(projf + ((nt * 6 + ks) * 64 + l) * 8);
      #pragma unroll
      for (int mt = 0; mt < 4; ++mt) pa[ntl][mt] = MFMA(a[mt], b, pa[ntl][mt]);
    }
  }
  #pragma unroll
  for (int ntl = 0; ntl < 2; ++ntl) {
    int col = (2 * h + ntl) * 16 + c16;
    float pb = loadf(proj_b, col, isb);
    #pragma unroll
    for (int mt = 0; mt < 4; ++mt)
      #pragma unroll
      for (int reg = 0; reg < 4; ++reg) {
        float vv = pa[ntl][mt][reg] + pb;
        size_t oi = (size_t)win * 12288 + (size_t)(mt * 16 + quad * 4 + reg) * 192 + col;
        if (isb) ((__bf16*)out)[oi] = (__bf16)vv;
        else     ((float*)out)[oi] = vv;
      }
  }
}

extern "C" void kernel_launch(void* const* d_in, const int* in_sizes, int n_in,
                              void* d_out, int out_size, void* d_ws, size_t ws_size,
                              hipStream_t stream) {
  (void)in_sizes; (void)n_in; (void)out_size; (void)ws_size;
  const void* x          = d_in[0];
  const void* mask       = d_in[1];
  const void* qkv_w      = d_in[2];
  const void* qkv_b      = d_in[3];
  const void* proj_w     = d_in[4];
  const void* proj_b     = d_in[5];
  const void* bias_table = d_in[6];
  const int*  rel_idx    = (const int*)d_in[7];

  char* ws = (char*)d_ws;
  int*    flag    = (int*)ws;                          // 4 B
  __bf16* qkv_wf  = (__bf16*)(ws + 256);               // 221184 B
  __bf16* projf   = (__bf16*)(ws + 256 + 221184);      // 73728 B
  float*  cmb     = (float*)(ws + 295168);             // 6291456 B

  detect_kernel<<<1, 256, 0, stream>>>(x, flag);
  prep_kernel<<<6720, 256, 0, stream>>>(qkv_w, proj_w, bias_table, rel_idx, mask, flag,
                                        qkv_wf, projf, cmb);
  wattn_kernel<<<8192, 384, 0, stream>>>(x, flag, qkv_wf, projf, cmb, qkv_b, proj_b, d_out);
}

// Round 3
// 949.163 us; speedup vs baseline: 1.1584x; 1.1584x over previous
//
#include <hip/hip_runtime.h>
#include <hip/hip_bf16.h>

typedef __bf16 v8bf __attribute__((ext_vector_type(8)));
typedef float  v4f  __attribute__((ext_vector_type(4)));

#define MFMA(a,b,c) __builtin_amdgcn_mfma_f32_16x16x32_bf16((a),(b),(c),0,0,0)

__device__ __forceinline__ float loadf(const void* p, int i, int isb) {
  return isb ? (float)(((const __bf16*)p)[i]) : ((const float*)p)[i];
}

// ---- K1: dtype detector (bf16 vs fp32 storage of float arrays) ----------
__global__ void detect_kernel(const void* __restrict__ x, int* __restrict__ flag) {
  __shared__ int cnt;
  if (threadIdx.x == 0) cnt = 0;
  __syncthreads();
  unsigned char b = ((const unsigned char*)x)[1 + 4 * (int)threadIdx.x];
  int e = b & 0x7f;
  if (e >= 0x3B && e <= 0x41) atomicAdd(&cnt, 1);
  __syncthreads();
  if (threadIdx.x == 0) *flag = (cnt >= 64) ? 1 : 0;
}

// ---- K2: weight repack (B-fragment order, bf16) + cmb = rpb + mask ------
// cmb layout: within each 64-col row, value for col j=jj*16+c16 stored at
// position c16*4+jj  -> wattn reads one float4 per (row, lane c16).
__global__ void prep_kernel(const void* __restrict__ qkv_w, const void* __restrict__ proj_w,
                            const void* __restrict__ bias_table, const int* __restrict__ rel_idx,
                            const void* __restrict__ mask, const int* __restrict__ flag,
                            __bf16* __restrict__ qkv_wf, __bf16* __restrict__ projf,
                            float* __restrict__ cmb) {
  const int isb = *flag;
  int e = blockIdx.x * 256 + threadIdx.x;
  if (e < 110592) {
    int j = e & 7, lx = (e >> 3) & 63, ks = (e >> 9) % 6, nt = e / 3072;
    int n = nt * 16 + (lx & 15), k = ks * 32 + (lx >> 4) * 8 + j;
    qkv_wf[e] = (__bf16)loadf(qkv_w, n * 192 + k, isb);
  } else if (e < 147456) {
    int e2 = e - 110592;
    int j = e2 & 7, lx = (e2 >> 3) & 63, ks = (e2 >> 9) % 6, nt = e2 / 3072;
    int n = nt * 16 + (lx & 15), k = ks * 32 + (lx >> 4) * 8 + j;
    projf[e2] = (__bf16)loadf(proj_w, n * 192 + k, isb);
  } else if (e < 147456 + 1572864) {
    int e2 = e - 147456;
    int j = e2 & 63, i = (e2 >> 6) & 63, hh = (e2 >> 12) % 6, w = e2 / 24576;
    float v = loadf(bias_table, rel_idx[i * 64 + j] * 6 + hh, isb)
            + loadf(mask, (w * 64 + i) * 64 + j, isb);
    cmb[(e2 & ~63) | (((j & 15) << 2) | (j >> 4))] = v;
  }
}

// ---- K3: fused window attention. 1 block = 2 windows, 12 waves ----------
// Occupancy was pinned at ONE workgroup/CU across 72KB/48KB LDS and 72/80
// VGPR variants -> the workgroup itself is the residency quantum. So pack
// 2 windows into one 768-thread block: 12 waves/CU (3/SIMD) instead of 6.
// Windows w and w+4096 share (win & 63)  -> same cmb slice and same weight
// fragments for same-head waves (L1 hits).
// LDS per window region (48KB): [0,24K) xf then vf; [24K,48K) per-head 4KB
// scratch (q/k/P bounce), then Of. Total 96KB.
__global__ __launch_bounds__(768, 3)
void wattn_kernel(const void* __restrict__ x, const int* __restrict__ flag,
                  const __bf16* __restrict__ qkv_wf, const __bf16* __restrict__ projf,
                  const float* __restrict__ cmb,
                  const void* __restrict__ qkv_b, const void* __restrict__ proj_b,
                  void* __restrict__ out) {
  __shared__ char smem[98304];

  const int isb = *flag;
  const int t = threadIdx.x;
  const int l = t & 63;
  const int wave = t >> 6;          // 0..11
  const int ww = wave / 6;          // local window 0/1
  const int h = wave - 6 * ww;      // head
  const int win = blockIdx.x + ww * 4096;
  const int quad = l >> 4;
  const int c16 = l & 15;
  const float SCALE = 0.17677669529663687f;   // 32^-0.5

  __bf16* xf = (__bf16*)(smem + ww * 49152);             // 24KB per window
  __bf16* Qs = (__bf16*)(smem + ww * 49152 + 24576);     // 24KB per window

  // ---- stage x (64x192) into A-fragment order, bf16 ----
  const int tl = t - ww * 384;                // thread within window group
  #pragma unroll
  for (int i = 0; i < 4; ++i) {
    int c = tl + i * 384;                     // c in [0,1536): 8 consecutive k's
    int tok = c / 24, kb8 = c % 24;
    v8bf v;
    if (isb) {
      v = *(const v8bf*)((const __bf16*)x + (size_t)win * 12288 + (size_t)c * 8);
    } else {
      const float* xp = (const float*)x + (size_t)win * 12288 + (size_t)c * 8;
      float4 f0 = ((const float4*)xp)[0];
      float4 f1 = ((const float4*)xp)[1];
      v8bf tv;
      tv[0]=(__bf16)f0.x; tv[1]=(__bf16)f0.y; tv[2]=(__bf16)f0.z; tv[3]=(__bf16)f0.w;
      tv[4]=(__bf16)f1.x; tv[5]=(__bf16)f1.y; tv[6]=(__bf16)f1.z; tv[7]=(__bf16)f1.w;
      v = tv;
    }
    int mt = tok >> 4, r = tok & 15, ks = kb8 >> 2, kb = kb8 & 3;
    *(v8bf*)(xf + ((mt * 6 + ks) * 64 + kb * 16 + r) * 8) = v;
  }
  __syncthreads();

  const v4f vzero = {0.f, 0.f, 0.f, 0.f};
  __bf16* sq = Qs + h * 2048;      // per-head 4KB scratch

  v8bf aq[4], bk[4];

  // ---- phase 1-qk: q then k projection, bounced through sq into regs ----
  #pragma unroll
  for (int pass = 0; pass < 2; ++pass) {
    v4f acc[2][4];
    #pragma unroll
    for (int n = 0; n < 2; ++n)
      #pragma unroll
      for (int m = 0; m < 4; ++m) acc[n][m] = vzero;

    #pragma unroll
    for (int ks = 0; ks < 6; ++ks) {
      v8bf a[4];
      #pragma unroll
      for (int mt = 0; mt < 4; ++mt) a[mt] = *(const v8bf*)(xf + ((mt * 6 + ks) * 64 + l) * 8);
      #pragma unroll
      for (int nl = 0; nl < 2; ++nl) {
        int nt = pass * 12 + 2 * h + nl;
        v8bf b = *(const v8bf*)(qkv_wf + ((nt * 6 + ks) * 64 + l) * 8);
        #pragma unroll
        for (int mt = 0; mt < 4; ++mt) acc[nl][mt] = MFMA(a[mt], b, acc[nl][mt]);
      }
    }
    float mul = pass ? 1.0f : SCALE;
    #pragma unroll
    for (int nl = 0; nl < 2; ++nl) {
      int hd = nl * 16 + c16;
      float bias = loadf(qkv_b, pass * 192 + h * 32 + hd, isb);
      #pragma unroll
      for (int mt = 0; mt < 4; ++mt)
        #pragma unroll
        for (int reg = 0; reg < 4; ++reg) {
          float vv = (acc[nl][mt][reg] + bias) * mul;
          int u = mt * 64 + (hd >> 3) * 16 + quad * 4 + reg;
          sq[u * 8 + (hd & 7)] = (__bf16)vv;
        }
    }
    if (pass == 0) {
      #pragma unroll
      for (int mt = 0; mt < 4; ++mt) aq[mt] = *(const v8bf*)(sq + (mt * 64 + l) * 8);
    } else {
      #pragma unroll
      for (int j = 0; j < 4; ++j) bk[j] = *(const v8bf*)(sq + (j * 64 + l) * 8);
    }
  }

  // ---- phase 1-v: v projection (M=64,N=32,K=192), still reads xf ----
  v4f vac[2][4];
  #pragma unroll
  for (int n = 0; n < 2; ++n)
    #pragma unroll
    for (int m = 0; m < 4; ++m) vac[n][m] = vzero;
  #pragma unroll
  for (int ks = 0; ks < 6; ++ks) {
    v8bf a[4];
    #pragma unroll
    for (int mt = 0; mt < 4; ++mt) a[mt] = *(const v8bf*)(xf + ((mt * 6 + ks) * 64 + l) * 8);
    #pragma unroll
    for (int ntl = 0; ntl < 2; ++ntl) {
      int nt = 24 + 2 * h + ntl;
      v8bf b = *(const v8bf*)(qkv_wf + ((nt * 6 + ks) * 64 + l) * 8);
      #pragma unroll
      for (int mt = 0; mt < 4; ++mt) vac[ntl][mt] = MFMA(a[mt], b, vac[ntl][mt]);
    }
  }
  __syncthreads();   // all waves done reading xf -> x region reusable

  __bf16* vf = xf + h * 2048;      // V in B-frag order (K=token', N=hd)
  #pragma unroll
  for (int ntl = 0; ntl < 2; ++ntl) {
    float bias = loadf(qkv_b, 384 + h * 32 + ntl * 16 + c16, isb);
    #pragma unroll
    for (int mt = 0; mt < 4; ++mt)
      #pragma unroll
      for (int reg = 0; reg < 4; ++reg) {
        int mrow = quad * 4 + reg;
        int u = (ntl * 2 + (mt >> 1)) * 64 + ((mt & 1) * 2 + (mrow >> 3)) * 16 + c16;
        vf[u * 8 + (mrow & 7)] = (__bf16)(vac[ntl][mt][reg] + bias);
      }
  }

  // ---- phase 2 (fused): scores + bias/mask + softmax + PV, per 16-row mt --
  v8bf bv[2][2];
  #pragma unroll
  for (int ksb = 0; ksb < 2; ++ksb)
    #pragma unroll
    for (int ntb = 0; ntb < 2; ++ntb)
      bv[ksb][ntb] = *(const v8bf*)(vf + ((ntb * 2 + ksb) * 64 + l) * 8);

  v4f o[4][2];
  #pragma unroll
  for (int m = 0; m < 4; ++m) { o[m][0] = vzero; o[m][1] = vzero; }

  {
    const float* cb = cmb + (size_t)((win & 63) * 6 + h) * 4096;
    #pragma unroll
    for (int mt = 0; mt < 4; ++mt) {
      v4f sc[4];
      #pragma unroll
      for (int j = 0; j < 4; ++j) sc[j] = MFMA(aq[mt], bk[j], vzero);
      #pragma unroll
      for (int reg = 0; reg < 4; ++reg) {
        int mrow = quad * 4 + reg;
        int row = mt * 16 + mrow;
        float4 cv = *(const float4*)(cb + row * 64 + c16 * 4);
        float v0 = sc[0][reg] + cv.x;
        float v1 = sc[1][reg] + cv.y;
        float v2 = sc[2][reg] + cv.z;
        float v3 = sc[3][reg] + cv.w;
        float mx = fmaxf(fmaxf(v0, v1), fmaxf(v2, v3));
        mx = fmaxf(mx, __shfl_xor(mx, 1));
        mx = fmaxf(mx, __shfl_xor(mx, 2));
        mx = fmaxf(mx, __shfl_xor(mx, 4));
        mx = fmaxf(mx, __shfl_xor(mx, 8));
        float p0 = __expf(v0 - mx), p1 = __expf(v1 - mx);
        float p2 = __expf(v2 - mx), p3 = __expf(v3 - mx);
        float sm = p0 + p1 + p2 + p3;
        sm += __shfl_xor(sm, 1);
        sm += __shfl_xor(sm, 2);
        sm += __shfl_xor(sm, 4);
        sm += __shfl_xor(sm, 8);
        float inv = 1.0f / sm;
        float pn[4] = {p0 * inv, p1 * inv, p2 * inv, p3 * inv};
        #pragma unroll
        for (int j = 0; j < 4; ++j) {
          int u = (j >> 1) * 64 + ((j & 1) * 2 + (c16 >> 3)) * 16 + mrow;
          sq[u * 8 + (c16 & 7)] = (__bf16)pn[j];   // P bounce (2KB, reused per mt)
        }
      }
      v8bf ap0 = *(const v8bf*)(sq + l * 8);
      v8bf ap1 = *(const v8bf*)(sq + (64 + l) * 8);
      o[mt][0] = MFMA(ap0, bv[0][0], o[mt][0]);
      o[mt][1] = MFMA(ap0, bv[0][1], o[mt][1]);
      o[mt][0] = MFMA(ap1, bv[1][0], o[mt][0]);
      o[mt][1] = MFMA(ap1, bv[1][1], o[mt][1]);
    }
  }
  __syncthreads();   // all P-bounce/vf reads done before Of overwrites scratch

  __bf16* Of = Qs;   // O (64x192) in A-frag order; wave h supplies k-step ks=h
  #pragma unroll
  for (int mt = 0; mt < 4; ++mt)
    #pragma unroll
    for (int ntb = 0; ntb < 2; ++ntb)
      #pragma unroll
      for (int reg = 0; reg < 4; ++reg) {
        int u = (mt * 6 + h) * 64 + (ntb * 2 + (c16 >> 3)) * 16 + quad * 4 + reg;
        Of[u * 8 + (c16 & 7)] = (__bf16)o[mt][ntb][reg];
      }
  __syncthreads();

  // ---- phase 3: out = O @ proj_w^T + proj_b (M=64,N=192,K=192) ----
  v4f pa[2][4];
  #pragma unroll
  for (int n = 0; n < 2; ++n)
    #pragma unroll
    for (int m = 0; m < 4; ++m) pa[n][m] = vzero;
  #pragma unroll
  for (int ks = 0; ks < 6; ++ks) {
    v8bf a[4];
    #pragma unroll
    for (int mt = 0; mt < 4; ++mt) a[mt] = *(const v8bf*)(Of + ((mt * 6 + ks) * 64 + l) * 8);
    #pragma unroll
    for (int ntl = 0; ntl < 2; ++ntl) {
      int nt = 2 * h + ntl;
      v8bf b = *(const v8bf*)(projf + ((nt * 6 + ks) * 64 + l) * 8);
      #pragma unroll
      for (int mt = 0; mt < 4; ++mt) pa[ntl][mt] = MFMA(a[mt], b, pa[ntl][mt]);
    }
  }
  #pragma unroll
  for (int ntl = 0; ntl < 2; ++ntl) {
    int col = (2 * h + ntl) * 16 + c16;
    float pb = loadf(proj_b, col, isb);
    #pragma unroll
    for (int mt = 0; mt < 4; ++mt)
      #pragma unroll
      for (int reg = 0; reg < 4; ++reg) {
        float vv = pa[ntl][mt][reg] + pb;
        size_t oi = (size_t)win * 12288 + (size_t)(mt * 16 + quad * 4 + reg) * 192 + col;
        if (isb) ((__bf16*)out)[oi] = (__bf16)vv;
        else     ((float*)out)[oi] = vv;
      }
  }
}

extern "C" void kernel_launch(void* const* d_in, const int* in_sizes, int n_in,
                              void* d_out, int out_size, void* d_ws, size_t ws_size,
                              hipStream_t stream) {
  (void)in_sizes; (void)n_in; (void)out_size; (void)ws_size;
  const void* x          = d_in[0];
  const void* mask       = d_in[1];
  const void* qkv_w      = d_in[2];
  const void* qkv_b      = d_in[3];
  const void* proj_w     = d_in[4];
  const void* proj_b     = d_in[5];
  const void* bias_table = d_in[6];
  const int*  rel_idx    = (const int*)d_in[7];

  char* ws = (char*)d_ws;
  int*    flag    = (int*)ws;                          // 4 B
  __bf16* qkv_wf  = (__bf16*)(ws + 256);               // 221184 B
  __bf16* projf   = (__bf16*)(ws + 256 + 221184);      // 73728 B
  float*  cmb     = (float*)(ws + 295168);             // 6291456 B

  detect_kernel<<<1, 256, 0, stream>>>(x, flag);
  prep_kernel<<<6720, 256, 0, stream>>>(qkv_w, proj_w, bias_table, rel_idx, mask, flag,
                                        qkv_wf, projf, cmb);
  wattn_kernel<<<4096, 768, 0, stream>>>(x, flag, qkv_wf, projf, cmb, qkv_b, proj_b, d_out);
}